// Round 5
// baseline (209.722 us; speedup 1.0000x reference)
//
#include <hip/hip_runtime.h>
#include <math.h>

#define DHID 128
#define NCLS 40

// ============ zero counts+ssum ==============================================
__global__ __launch_bounds__(256) void zero_kernel(
    int* __restrict__ counts, float* __restrict__ ssum, int n) {
  int i = blockIdx.x * 256 + threadIdx.x;
  if (i < n) { counts[i] = 0; ssum[i] = 0.f; }
}

// ============ CSR build (graph-static, once) ================================
__global__ __launch_bounds__(256) void build_count_kernel(
    const int* __restrict__ ei, const float* __restrict__ norm,
    int* __restrict__ counts, float* __restrict__ ssum, int E, int EP) {
  int k = blockIdx.x * blockDim.x + threadIdx.x;
  if (k >= EP) return;
  int src, dst;
  if (k < E) { src = ei[k]; dst = ei[E + k]; }
  else       { src = dst = k - E; }
  atomicAdd(&counts[dst], 1);
  atomicAdd(&ssum[src], __expf(norm[k]));
}

__global__ __launch_bounds__(1024) void scan_kernel(
    const int* __restrict__ counts, int* __restrict__ rowptr,
    int* __restrict__ nxt, int n) {
  __shared__ int sums[1024];
  int t = threadIdx.x;
  int per = (n + 1023) >> 10;
  int beg = t * per;
  int end = beg + per; if (end > n) end = n; if (beg > n) beg = n;
  int s = 0;
  for (int i = beg; i < end; ++i) s += counts[i];
  sums[t] = s;
  __syncthreads();
  for (int off = 1; off < 1024; off <<= 1) {
    int v = (t >= off) ? sums[t - off] : 0;
    __syncthreads();
    sums[t] += v;
    __syncthreads();
  }
  int run = (t == 0) ? 0 : sums[t - 1];
  for (int i = beg; i < end; ++i) {
    rowptr[i] = run; nxt[i] = run; run += counts[i];
  }
  if (t == 1023) rowptr[n] = sums[1023];
}

// scatter stores raw exp(norm); the 1/ssum[dst] factor is applied in agg
__global__ __launch_bounds__(256) void build_scatter_kernel(
    const int* __restrict__ ei, const float* __restrict__ norm,
    int* __restrict__ nxt, int* __restrict__ srcs, float* __restrict__ sexp,
    int E, int EP) {
  int k = blockIdx.x * blockDim.x + threadIdx.x;
  if (k >= EP) return;
  int src, dst;
  if (k < E) { src = ei[k]; dst = ei[E + k]; }
  else       { src = dst = k - E; }
  int pos = atomicAdd(&nxt[dst], 1);
  srcs[pos] = src;
  sexp[pos] = __expf(norm[k]);
}

// ============ per-node max-aggregation (one wave), register-broadcast =======
__device__ __forceinline__ float4 agg_node(
    const float* __restrict__ H, const int* __restrict__ rowptr,
    const int* __restrict__ srcs, const float* __restrict__ sexp,
    const float* __restrict__ el, const float* __restrict__ ssum,
    float base, float al, int node, int lane) {
  int beg = rowptr[node], end = rowptr[node + 1];
  int deg = end - beg;
  int src0 = 0; float e0 = 0.f, sx0 = 0.f;
  if (lane < deg) {
    src0 = srcs[beg + lane];
    sx0  = sexp[beg + lane];
    float g = el[src0] + base;
    e0 = __expf(g > 0.f ? g : 0.2f * g);
  }
  float es = e0;
  for (int cb = beg + 64; cb < end; cb += 64) {   // rare: deg > 64
    int s2 = cb + lane;
    if (s2 < end) {
      float g = el[srcs[s2]] + base;
      es += __expf(g > 0.f ? g : 0.2f * g);
    }
  }
#pragma unroll
  for (int off = 32; off; off >>= 1) es += __shfl_xor(es, off);
  float invEs = al / es;
  float omaS  = (1.f - al) / ssum[node];
  float w0 = e0 * invEs + sx0 * omaS;

  int half = lane >> 5;
  int fl = (lane & 31) << 2;
  float4 acc = make_float4(-INFINITY, -INFINITY, -INFINITY, -INFINITY);
  int cnt = deg < 64 ? deg : 64;
  int jj = half;
  for (; jj + 2 < cnt; jj += 4) {
    int   sa = __shfl(src0, jj);
    int   sb = __shfl(src0, jj + 2);
    float wa = __shfl(w0, jj);
    float wb = __shfl(w0, jj + 2);
    float4 ha = *reinterpret_cast<const float4*>(H + (size_t)sa * DHID + fl);
    float4 hb = *reinterpret_cast<const float4*>(H + (size_t)sb * DHID + fl);
    acc.x = fmaxf(acc.x, fmaxf(wa * ha.x, wb * hb.x));
    acc.y = fmaxf(acc.y, fmaxf(wa * ha.y, wb * hb.y));
    acc.z = fmaxf(acc.z, fmaxf(wa * ha.z, wb * hb.z));
    acc.w = fmaxf(acc.w, fmaxf(wa * ha.w, wb * hb.w));
  }
  if (jj < cnt) {
    int   sa = __shfl(src0, jj);
    float wa = __shfl(w0, jj);
    float4 ha = *reinterpret_cast<const float4*>(H + (size_t)sa * DHID + fl);
    acc.x = fmaxf(acc.x, wa * ha.x);
    acc.y = fmaxf(acc.y, wa * ha.y);
    acc.z = fmaxf(acc.z, wa * ha.z);
    acc.w = fmaxf(acc.w, wa * ha.w);
  }
  for (int cb = beg + 64; cb < end; cb += 64) {   // rare: deg > 64
    int s2 = cb + lane;
    int srcc = 0; float wc = 0.f;
    if (s2 < end) {
      srcc = srcs[s2];
      float g = el[srcc] + base;
      wc = __expf(g > 0.f ? g : 0.2f * g) * invEs + sexp[s2] * omaS;
    }
    int cnt2 = end - cb; if (cnt2 > 64) cnt2 = 64;
    int q = half;
    for (; q + 2 < cnt2; q += 4) {
      int   sa = __shfl(srcc, q);
      int   sb = __shfl(srcc, q + 2);
      float wa = __shfl(wc, q);
      float wb = __shfl(wc, q + 2);
      float4 ha = *reinterpret_cast<const float4*>(H + (size_t)sa * DHID + fl);
      float4 hb = *reinterpret_cast<const float4*>(H + (size_t)sb * DHID + fl);
      acc.x = fmaxf(acc.x, fmaxf(wa * ha.x, wb * hb.x));
      acc.y = fmaxf(acc.y, fmaxf(wa * ha.y, wb * hb.y));
      acc.z = fmaxf(acc.z, fmaxf(wa * ha.z, wb * hb.z));
      acc.w = fmaxf(acc.w, fmaxf(wa * ha.w, wb * hb.w));
    }
    if (q < cnt2) {
      int   sa = __shfl(srcc, q);
      float wa = __shfl(wc, q);
      float4 ha = *reinterpret_cast<const float4*>(H + (size_t)sa * DHID + fl);
      acc.x = fmaxf(acc.x, wa * ha.x);
      acc.y = fmaxf(acc.y, wa * ha.y);
      acc.z = fmaxf(acc.z, wa * ha.z);
      acc.w = fmaxf(acc.w, wa * ha.w);
    }
  }
  acc.x = fmaxf(acc.x, __shfl_xor(acc.x, 32));
  acc.y = fmaxf(acc.y, __shfl_xor(acc.y, 32));
  acc.z = fmaxf(acc.z, __shfl_xor(acc.z, 32));
  acc.w = fmaxf(acc.w, __shfl_xor(acc.w, 32));
  return acc;
}

// ============ shared GEMM+elr body: Xs (32x128 in LDS) @ W -> Hout, el, er ===
__device__ __forceinline__ void gemm_from_lds(
    float* Ws, float* Xs, const float* __restrict__ W,
    const float* __restrict__ aW, float* __restrict__ Hout,
    float* __restrict__ elo, float* __restrict__ ero, int n, int rowBase) {
  int t = threadIdx.x;
  int rg = t >> 5;
  int c0 = (t & 31) << 2;
  float acc[4][4];
#pragma unroll
  for (int j = 0; j < 4; ++j)
#pragma unroll
    for (int c = 0; c < 4; ++c) acc[j][c] = 0.f;

  for (int kt = 0; kt < 2; ++kt) {
    __syncthreads();
    const float* Wsrc = W + kt * 64 * DHID;
#pragma unroll
    for (int q = 0; q < 8; ++q) {
      int i4 = t + q * 256;
      *reinterpret_cast<float4*>(Ws + i4 * 4) =
          *reinterpret_cast<const float4*>(Wsrc + i4 * 4);
    }
    __syncthreads();
#pragma unroll 2
    for (int k = 0; k < 64; k += 4) {
      float4 xv[4];
#pragma unroll
      for (int j = 0; j < 4; ++j)
        xv[j] = *reinterpret_cast<const float4*>(
            Xs + (rg * 4 + j) * DHID + kt * 64 + k);
#pragma unroll
      for (int kk = 0; kk < 4; ++kk) {
        float4 wv = *reinterpret_cast<const float4*>(Ws + (k + kk) * DHID + c0);
#pragma unroll
        for (int j = 0; j < 4; ++j) {
          float xj = (&xv[j].x)[kk];
          acc[j][0] = fmaf(xj, wv.x, acc[j][0]);
          acc[j][1] = fmaf(xj, wv.y, acc[j][1]);
          acc[j][2] = fmaf(xj, wv.z, acc[j][2]);
          acc[j][3] = fmaf(xj, wv.w, acc[j][3]);
        }
      }
    }
  }

#pragma unroll
  for (int j = 0; j < 4; ++j) {
    int gr = rowBase + rg * 4 + j;
    if (gr < n)
      *reinterpret_cast<float4*>(Hout + (size_t)gr * DHID + c0) =
          make_float4(acc[j][0], acc[j][1], acc[j][2], acc[j][3]);
  }

  float4 al4 = *reinterpret_cast<const float4*>(aW + c0);
  float4 ar4 = *reinterpret_cast<const float4*>(aW + DHID + c0);
  __syncthreads();
  float* P = Xs;                    // reuse as P[2][32][33]
#pragma unroll
  for (int j = 0; j < 4; ++j) {
    int r = rg * 4 + j;
    float pl = acc[j][0] * al4.x + acc[j][1] * al4.y +
               acc[j][2] * al4.z + acc[j][3] * al4.w;
    float pr = acc[j][0] * ar4.x + acc[j][1] * ar4.y +
               acc[j][2] * ar4.z + acc[j][3] * ar4.w;
    P[r * 33 + (t & 31)] = pl;
    P[1056 + r * 33 + (t & 31)] = pr;
  }
  __syncthreads();
  if (t < 64) {
    int half = t >> 5, r = t & 31;
    const float* Pr = P + half * 1056 + r * 33;
    float s = 0.f;
#pragma unroll
    for (int c = 0; c < 32; ++c) s += Pr[c];
    int gr = rowBase + r;
    if (gr < n) { if (half) ero[gr] = s; else elo[gr] = s; }
  }
}

// ============ K1: H1 = X @ W1  (+ el1, er1) =================================
__global__ __launch_bounds__(256) void gemm_elr_kernel(
    const float* __restrict__ X, const float* __restrict__ W,
    const float* __restrict__ aW, float* __restrict__ H,
    float* __restrict__ el, float* __restrict__ er, int n) {
  __shared__ float Ws[64 * 128];
  __shared__ float Xs[32 * 128];
  int t = threadIdx.x;
  int rowBase = blockIdx.x * 32;
#pragma unroll
  for (int q = 0; q < 4; ++q) {
    int i4 = t + q * 256;
    int r = i4 >> 5, c = (i4 & 31) << 2;
    int gr = rowBase + r;
    float4 v = (gr < n)
        ? *reinterpret_cast<const float4*>(X + (size_t)gr * DHID + c)
        : make_float4(0.f, 0.f, 0.f, 0.f);
    *reinterpret_cast<float4*>(Xs + r * DHID + c) = v;
  }
  gemm_from_lds(Ws, Xs, W, aW, H, el, er, n, rowBase);
}

// ============ K2: agg(layer L) -> Xs (8 nodes/wave!), then @ W(L+1) =========
__global__ __launch_bounds__(256) void agg_gemm_elr_kernel(
    const float* __restrict__ H, const int* __restrict__ rowptr,
    const int* __restrict__ srcs, const float* __restrict__ sexp,
    const float* __restrict__ el_in, const float* __restrict__ er_in,
    const float* __restrict__ ssum, const float* __restrict__ ab,
    const float* __restrict__ alpha, const float* __restrict__ bias,
    const float* __restrict__ W, const float* __restrict__ aW,
    float* __restrict__ Hout, float* __restrict__ el_out,
    float* __restrict__ er_out, int n) {
  __shared__ float Ws[64 * 128];
  __shared__ float Xs[32 * 128];
  int t = threadIdx.x;
  int wv = t >> 6, lane = t & 63;
  int rowBase = blockIdx.x * 32;
  float al = fminf(fmaxf(alpha[0], 1e-4f), 0.9999f);
  float abv = ab[0];
#pragma unroll 1
  for (int j = 0; j < 8; ++j) {          // 4 waves x 8 nodes = 32 rows
    int r = wv * 8 + j;
    int node = rowBase + r;
    float4 acc = make_float4(0.f, 0.f, 0.f, 0.f);
    if (node < n) {
      float base = er_in[node] + abv;
      acc = agg_node(H, rowptr, srcs, sexp, el_in, ssum, base, al, node, lane);
    }
    if (lane < 32) {
      int fl = lane << 2;
      float4 o = make_float4(0.f, 0.f, 0.f, 0.f);
      if (node < n) {
        float4 b = *reinterpret_cast<const float4*>(bias + fl);
        o.x = fmaxf(acc.x + b.x, 0.f);
        o.y = fmaxf(acc.y + b.y, 0.f);
        o.z = fmaxf(acc.z + b.z, 0.f);
        o.w = fmaxf(acc.w + b.w, 0.f);
      }
      *reinterpret_cast<float4*>(Xs + r * DHID + fl) = o;
    }
  }
  gemm_from_lds(Ws, Xs, W, aW, Hout, el_out, er_out, n, rowBase);
}

// ============ K3: agg(layer 2) -> hl (8 nodes/wave), then log_softmax head ==
__global__ __launch_bounds__(256) void agg_head_kernel(
    const float* __restrict__ H, const int* __restrict__ rowptr,
    const int* __restrict__ srcs, const float* __restrict__ sexp,
    const float* __restrict__ el_in, const float* __restrict__ er_in,
    const float* __restrict__ ssum, const float* __restrict__ ab,
    const float* __restrict__ alpha, const float* __restrict__ bias,
    const float* __restrict__ Wout, const float* __restrict__ bout,
    float* __restrict__ out, int n) {
  __shared__ float Wl[DHID * NCLS];   // 20 KB
  __shared__ float hl[32 * DHID];     // 16 KB
  int t = threadIdx.x;
  for (int i = t; i < DHID * NCLS; i += 256) Wl[i] = Wout[i];
  int wv = t >> 6, lane = t & 63;
  int rowBase = blockIdx.x * 32;
  float al = fminf(fmaxf(alpha[0], 1e-4f), 0.9999f);
  float abv = ab[0];
#pragma unroll 1
  for (int j = 0; j < 8; ++j) {          // 4 waves x 8 nodes = 32 rows
    int r = wv * 8 + j;
    int node = rowBase + r;
    float4 acc = make_float4(0.f, 0.f, 0.f, 0.f);
    if (node < n) {
      float base = er_in[node] + abv;
      acc = agg_node(H, rowptr, srcs, sexp, el_in, ssum, base, al, node, lane);
    }
    if (lane < 32) {
      int fl = lane << 2;
      float4 o = make_float4(0.f, 0.f, 0.f, 0.f);
      if (node < n) {
        float4 b = *reinterpret_cast<const float4*>(bias + fl);
        o.x = fmaxf(acc.x + b.x, 0.f);
        o.y = fmaxf(acc.y + b.y, 0.f);
        o.z = fmaxf(acc.z + b.z, 0.f);
        o.w = fmaxf(acc.w + b.w, 0.f);
      }
      *reinterpret_cast<float4*>(hl + r * DHID + fl) = o;
    }
  }
  __syncthreads();
#pragma unroll 1
  for (int j = 0; j < 8; ++j) {
    int r = wv * 8 + j;
    int node = rowBase + r;
    if (node >= n) continue;          // wave-uniform: safe with shfl below
    float z = -INFINITY;
    bool act = lane < NCLS;
    if (act) {
      z = bout[lane];
      const float* hr = hl + r * DHID;
#pragma unroll 8
      for (int k = 0; k < DHID; ++k) z = fmaf(hr[k], Wl[k * NCLS + lane], z);
    }
    float m = z;
#pragma unroll
    for (int off = 32; off; off >>= 1) m = fmaxf(m, __shfl_xor(m, off));
    float p = act ? expf(z - m) : 0.f;
#pragma unroll
    for (int off = 32; off; off >>= 1) p += __shfl_xor(p, off);
    float ls = logf(p);
    if (act) out[(size_t)node * NCLS + lane] = z - m - ls;
  }
}

// ===========================================================================
extern "C" void kernel_launch(void* const* d_in, const int* in_sizes, int n_in,
                              void* d_out, int out_size, void* d_ws, size_t ws_size,
                              hipStream_t stream) {
  const float* x     = (const float*)d_in[0];
  const int*   ei    = (const int*)d_in[1];
  const float* norm  = (const float*)d_in[2];
  const float* W1    = (const float*)d_in[3];
  const float* aW1   = (const float*)d_in[4];
  const float* ab1   = (const float*)d_in[5];
  const float* alpha1= (const float*)d_in[6];
  const float* b1    = (const float*)d_in[7];
  const float* W2    = (const float*)d_in[8];
  const float* aW2   = (const float*)d_in[9];
  const float* ab2   = (const float*)d_in[10];
  const float* alpha2= (const float*)d_in[11];
  const float* b2    = (const float*)d_in[12];
  const float* Wout  = (const float*)d_in[13];
  const float* bout  = (const float*)d_in[14];
  float* out = (float*)d_out;

  const int N  = in_sizes[0] / DHID;
  const int E  = in_sizes[1] / 2;
  const int EP = E + N;

  char* ws = (char*)d_ws;
  size_t off = 0;
  auto alloc = [&](size_t bytes) -> void* {
    void* p = ws + off;
    off += (bytes + 255) & ~(size_t)255;
    return p;
  };
  int*   counts = (int*)  alloc((size_t)N * 4);
  float* ssum   = (float*)alloc((size_t)N * 4);
  float* A      = (float*)alloc((size_t)N * DHID * 4);  // layer-1 H
  float* A2     = (float*)alloc((size_t)N * DHID * 4);  // layer-2 H
  float* el1    = (float*)alloc((size_t)N * 4);
  float* er1    = (float*)alloc((size_t)N * 4);
  float* el2    = (float*)alloc((size_t)N * 4);
  float* er2    = (float*)alloc((size_t)N * 4);
  int*   rowptr = (int*)  alloc((size_t)(N + 1) * 4);
  int*   nxt    = (int*)  alloc((size_t)N * 4);
  int*   srcs   = (int*)  alloc((size_t)EP * 4);
  float* sexp   = (float*)alloc((size_t)EP * 4);

  const int gZero = (N + 255) / 256;
  const int gEdge = (EP + 255) / 256;
  const int gT    = (N + 31) / 32;

  // graph-static build
  zero_kernel<<<gZero, 256, 0, stream>>>(counts, ssum, N);
  build_count_kernel<<<gEdge, 256, 0, stream>>>(ei, norm, counts, ssum, E, EP);
  scan_kernel<<<1, 1024, 0, stream>>>(counts, rowptr, nxt, N);
  build_scatter_kernel<<<gEdge, 256, 0, stream>>>(ei, norm, nxt, srcs, sexp,
                                                  E, EP);
  // layer 1 GEMM (+projections)
  gemm_elr_kernel<<<gT, 256, 0, stream>>>(x, W1, aW1, A, el1, er1, N);
  // agg(layer1) fused with layer-2 GEMM (+projections)
  agg_gemm_elr_kernel<<<gT, 256, 0, stream>>>(A, rowptr, srcs, sexp, el1, er1,
                                              ssum, ab1, alpha1, b1, W2, aW2,
                                              A2, el2, er2, N);
  // agg(layer2) fused with output head
  agg_head_kernel<<<gT, 256, 0, stream>>>(A2, rowptr, srcs, sexp, el2, er2,
                                          ssum, ab2, alpha2, b2, Wout, bout,
                                          out, N);
}

// Round 6
// 200.331 us; speedup vs baseline: 1.0469x; 1.0469x over previous
//
#include <hip/hip_runtime.h>
#include <math.h>

#define DHID 128
#define NCLS 40

// ============ zero counts+ssum ==============================================
__global__ __launch_bounds__(256) void zero_kernel(
    int* __restrict__ counts, float* __restrict__ ssum, int n) {
  int i = blockIdx.x * 256 + threadIdx.x;
  if (i < n) { counts[i] = 0; ssum[i] = 0.f; }
}

// ============ CSR build (graph-static, once) ================================
__global__ __launch_bounds__(256) void build_count_kernel(
    const int* __restrict__ ei, const float* __restrict__ norm,
    int* __restrict__ counts, float* __restrict__ ssum, int E, int EP) {
  int k = blockIdx.x * blockDim.x + threadIdx.x;
  if (k >= EP) return;
  int src, dst;
  if (k < E) { src = ei[k]; dst = ei[E + k]; }
  else       { src = dst = k - E; }
  atomicAdd(&counts[dst], 1);
  atomicAdd(&ssum[src], __expf(norm[k]));
}

__global__ __launch_bounds__(1024) void scan_kernel(
    const int* __restrict__ counts, int* __restrict__ rowptr,
    int* __restrict__ nxt, int n) {
  __shared__ int sums[1024];
  int t = threadIdx.x;
  int per = (n + 1023) >> 10;
  int beg = t * per;
  int end = beg + per; if (end > n) end = n; if (beg > n) beg = n;
  int s = 0;
  for (int i = beg; i < end; ++i) s += counts[i];
  sums[t] = s;
  __syncthreads();
  for (int off = 1; off < 1024; off <<= 1) {
    int v = (t >= off) ? sums[t - off] : 0;
    __syncthreads();
    sums[t] += v;
    __syncthreads();
  }
  int run = (t == 0) ? 0 : sums[t - 1];
  for (int i = beg; i < end; ++i) {
    rowptr[i] = run; nxt[i] = run; run += counts[i];
  }
  if (t == 1023) rowptr[n] = sums[1023];
}

// scatter stores raw exp(norm); the 1/ssum[dst] factor is applied in agg
__global__ __launch_bounds__(256) void build_scatter_kernel(
    const int* __restrict__ ei, const float* __restrict__ norm,
    int* __restrict__ nxt, int* __restrict__ srcs, float* __restrict__ sexp,
    int E, int EP) {
  int k = blockIdx.x * blockDim.x + threadIdx.x;
  if (k >= EP) return;
  int src, dst;
  if (k < E) { src = ei[k]; dst = ei[E + k]; }
  else       { src = dst = k - E; }
  int pos = atomicAdd(&nxt[dst], 1);
  srcs[pos] = src;
  sexp[pos] = __expf(norm[k]);
}

// ============ per-node max-aggregation (one wave), register-broadcast =======
__device__ __forceinline__ float4 agg_node(
    const float* __restrict__ H, const int* __restrict__ rowptr,
    const int* __restrict__ srcs, const float* __restrict__ sexp,
    const float* __restrict__ el, const float* __restrict__ ssum,
    float base, float al, int node, int lane) {
  int beg = rowptr[node], end = rowptr[node + 1];
  int deg = end - beg;
  int src0 = 0; float e0 = 0.f, sx0 = 0.f;
  if (lane < deg) {
    src0 = srcs[beg + lane];
    sx0  = sexp[beg + lane];
    float g = el[src0] + base;
    e0 = __expf(g > 0.f ? g : 0.2f * g);
  }
  float es = e0;
  for (int cb = beg + 64; cb < end; cb += 64) {   // rare: deg > 64
    int s2 = cb + lane;
    if (s2 < end) {
      float g = el[srcs[s2]] + base;
      es += __expf(g > 0.f ? g : 0.2f * g);
    }
  }
#pragma unroll
  for (int off = 32; off; off >>= 1) es += __shfl_xor(es, off);
  float invEs = al / es;
  float omaS  = (1.f - al) / ssum[node];
  float w0 = e0 * invEs + sx0 * omaS;

  int half = lane >> 5;
  int fl = (lane & 31) << 2;
  float4 acc = make_float4(-INFINITY, -INFINITY, -INFINITY, -INFINITY);
  int cnt = deg < 64 ? deg : 64;
  int jj = half;
  for (; jj + 2 < cnt; jj += 4) {
    int   sa = __shfl(src0, jj);
    int   sb = __shfl(src0, jj + 2);
    float wa = __shfl(w0, jj);
    float wb = __shfl(w0, jj + 2);
    float4 ha = *reinterpret_cast<const float4*>(H + (size_t)sa * DHID + fl);
    float4 hb = *reinterpret_cast<const float4*>(H + (size_t)sb * DHID + fl);
    acc.x = fmaxf(acc.x, fmaxf(wa * ha.x, wb * hb.x));
    acc.y = fmaxf(acc.y, fmaxf(wa * ha.y, wb * hb.y));
    acc.z = fmaxf(acc.z, fmaxf(wa * ha.z, wb * hb.z));
    acc.w = fmaxf(acc.w, fmaxf(wa * ha.w, wb * hb.w));
  }
  if (jj < cnt) {
    int   sa = __shfl(src0, jj);
    float wa = __shfl(w0, jj);
    float4 ha = *reinterpret_cast<const float4*>(H + (size_t)sa * DHID + fl);
    acc.x = fmaxf(acc.x, wa * ha.x);
    acc.y = fmaxf(acc.y, wa * ha.y);
    acc.z = fmaxf(acc.z, wa * ha.z);
    acc.w = fmaxf(acc.w, wa * ha.w);
  }
  for (int cb = beg + 64; cb < end; cb += 64) {   // rare: deg > 64
    int s2 = cb + lane;
    int srcc = 0; float wc = 0.f;
    if (s2 < end) {
      srcc = srcs[s2];
      float g = el[srcc] + base;
      wc = __expf(g > 0.f ? g : 0.2f * g) * invEs + sexp[s2] * omaS;
    }
    int cnt2 = end - cb; if (cnt2 > 64) cnt2 = 64;
    int q = half;
    for (; q + 2 < cnt2; q += 4) {
      int   sa = __shfl(srcc, q);
      int   sb = __shfl(srcc, q + 2);
      float wa = __shfl(wc, q);
      float wb = __shfl(wc, q + 2);
      float4 ha = *reinterpret_cast<const float4*>(H + (size_t)sa * DHID + fl);
      float4 hb = *reinterpret_cast<const float4*>(H + (size_t)sb * DHID + fl);
      acc.x = fmaxf(acc.x, fmaxf(wa * ha.x, wb * hb.x));
      acc.y = fmaxf(acc.y, fmaxf(wa * ha.y, wb * hb.y));
      acc.z = fmaxf(acc.z, fmaxf(wa * ha.z, wb * hb.z));
      acc.w = fmaxf(acc.w, fmaxf(wa * ha.w, wb * hb.w));
    }
    if (q < cnt2) {
      int   sa = __shfl(srcc, q);
      float wa = __shfl(wc, q);
      float4 ha = *reinterpret_cast<const float4*>(H + (size_t)sa * DHID + fl);
      acc.x = fmaxf(acc.x, wa * ha.x);
      acc.y = fmaxf(acc.y, wa * ha.y);
      acc.z = fmaxf(acc.z, wa * ha.z);
      acc.w = fmaxf(acc.w, wa * ha.w);
    }
  }
  acc.x = fmaxf(acc.x, __shfl_xor(acc.x, 32));
  acc.y = fmaxf(acc.y, __shfl_xor(acc.y, 32));
  acc.z = fmaxf(acc.z, __shfl_xor(acc.z, 32));
  acc.w = fmaxf(acc.w, __shfl_xor(acc.w, 32));
  return acc;
}

// ============ standalone agg: Y[node] = relu(max_e w*H[src] + bias) =========
// 1 node per wave, 4 waves/block, grid N/4 -> full occupancy, no LDS.
__global__ __launch_bounds__(256) void agg_kernel(
    const float* __restrict__ H, const int* __restrict__ rowptr,
    const int* __restrict__ srcs, const float* __restrict__ sexp,
    const float* __restrict__ el, const float* __restrict__ er,
    const float* __restrict__ ssum, const float* __restrict__ ab,
    const float* __restrict__ alpha, const float* __restrict__ bias,
    float* __restrict__ Y, int n) {
  int node = blockIdx.x * 4 + (threadIdx.x >> 6);
  int lane = threadIdx.x & 63;
  if (node >= n) return;
  float al = fminf(fmaxf(alpha[0], 1e-4f), 0.9999f);
  float base = er[node] + ab[0];
  float4 acc = agg_node(H, rowptr, srcs, sexp, el, ssum, base, al, node, lane);
  if (lane < 32) {
    int fl = lane << 2;
    float4 b = *reinterpret_cast<const float4*>(bias + fl);
    float4 o;
    o.x = fmaxf(acc.x + b.x, 0.f);
    o.y = fmaxf(acc.y + b.y, 0.f);
    o.z = fmaxf(acc.z + b.z, 0.f);
    o.w = fmaxf(acc.w + b.w, 0.f);
    *reinterpret_cast<float4*>(Y + (size_t)node * DHID + fl) = o;
  }
}

// ============ shared GEMM+elr body: Xs (32x128 in LDS) @ W -> Hout, el, er ===
__device__ __forceinline__ void gemm_from_lds(
    float* Ws, float* Xs, const float* __restrict__ W,
    const float* __restrict__ aW, float* __restrict__ Hout,
    float* __restrict__ elo, float* __restrict__ ero, int n, int rowBase) {
  int t = threadIdx.x;
  int rg = t >> 5;
  int c0 = (t & 31) << 2;
  float acc[4][4];
#pragma unroll
  for (int j = 0; j < 4; ++j)
#pragma unroll
    for (int c = 0; c < 4; ++c) acc[j][c] = 0.f;

  for (int kt = 0; kt < 2; ++kt) {
    __syncthreads();
    const float* Wsrc = W + kt * 64 * DHID;
#pragma unroll
    for (int q = 0; q < 8; ++q) {
      int i4 = t + q * 256;
      *reinterpret_cast<float4*>(Ws + i4 * 4) =
          *reinterpret_cast<const float4*>(Wsrc + i4 * 4);
    }
    __syncthreads();
#pragma unroll 2
    for (int k = 0; k < 64; k += 4) {
      float4 xv[4];
#pragma unroll
      for (int j = 0; j < 4; ++j)
        xv[j] = *reinterpret_cast<const float4*>(
            Xs + (rg * 4 + j) * DHID + kt * 64 + k);
#pragma unroll
      for (int kk = 0; kk < 4; ++kk) {
        float4 wv = *reinterpret_cast<const float4*>(Ws + (k + kk) * DHID + c0);
#pragma unroll
        for (int j = 0; j < 4; ++j) {
          float xj = (&xv[j].x)[kk];
          acc[j][0] = fmaf(xj, wv.x, acc[j][0]);
          acc[j][1] = fmaf(xj, wv.y, acc[j][1]);
          acc[j][2] = fmaf(xj, wv.z, acc[j][2]);
          acc[j][3] = fmaf(xj, wv.w, acc[j][3]);
        }
      }
    }
  }

#pragma unroll
  for (int j = 0; j < 4; ++j) {
    int gr = rowBase + rg * 4 + j;
    if (gr < n)
      *reinterpret_cast<float4*>(Hout + (size_t)gr * DHID + c0) =
          make_float4(acc[j][0], acc[j][1], acc[j][2], acc[j][3]);
  }

  float4 al4 = *reinterpret_cast<const float4*>(aW + c0);
  float4 ar4 = *reinterpret_cast<const float4*>(aW + DHID + c0);
  __syncthreads();
  float* P = Xs;                    // reuse as P[2][32][33]
#pragma unroll
  for (int j = 0; j < 4; ++j) {
    int r = rg * 4 + j;
    float pl = acc[j][0] * al4.x + acc[j][1] * al4.y +
               acc[j][2] * al4.z + acc[j][3] * al4.w;
    float pr = acc[j][0] * ar4.x + acc[j][1] * ar4.y +
               acc[j][2] * ar4.z + acc[j][3] * ar4.w;
    P[r * 33 + (t & 31)] = pl;
    P[1056 + r * 33 + (t & 31)] = pr;
  }
  __syncthreads();
  if (t < 64) {
    int half = t >> 5, r = t & 31;
    const float* Pr = P + half * 1056 + r * 33;
    float s = 0.f;
#pragma unroll
    for (int c = 0; c < 32; ++c) s += Pr[c];
    int gr = rowBase + r;
    if (gr < n) { if (half) ero[gr] = s; else elo[gr] = s; }
  }
}

// ============ GEMM: H = X @ W  (+ el, er) ===================================
__global__ __launch_bounds__(256) void gemm_elr_kernel(
    const float* __restrict__ X, const float* __restrict__ W,
    const float* __restrict__ aW, float* __restrict__ H,
    float* __restrict__ el, float* __restrict__ er, int n) {
  __shared__ float Ws[64 * 128];
  __shared__ float Xs[32 * 128];
  int t = threadIdx.x;
  int rowBase = blockIdx.x * 32;
#pragma unroll
  for (int q = 0; q < 4; ++q) {
    int i4 = t + q * 256;
    int r = i4 >> 5, c = (i4 & 31) << 2;
    int gr = rowBase + r;
    float4 v = (gr < n)
        ? *reinterpret_cast<const float4*>(X + (size_t)gr * DHID + c)
        : make_float4(0.f, 0.f, 0.f, 0.f);
    *reinterpret_cast<float4*>(Xs + r * DHID + c) = v;
  }
  gemm_from_lds(Ws, Xs, W, aW, H, el, er, n, rowBase);
}

// ============ head: out = log_softmax(H @ Wout + bout), 16 nodes/block =======
__global__ __launch_bounds__(256) void head_kernel(
    const float* __restrict__ H, const float* __restrict__ Wout,
    const float* __restrict__ bout, float* __restrict__ out, int n) {
  __shared__ float Wl[DHID * NCLS];  // 20 KB
  __shared__ float hl[4][DHID];
  int t = threadIdx.x;
  for (int i = t; i < DHID * NCLS; i += 256) Wl[i] = Wout[i];
  int w = t >> 6, lane = t & 63;
  __syncthreads();
  for (int nd = 0; nd < 4; ++nd) {
    int node = blockIdx.x * 16 + nd * 4 + w;
    if (node < n) {
      const float* hrow = H + (size_t)node * DHID;
      hl[w][lane] = hrow[lane];
      hl[w][lane + 64] = hrow[lane + 64];
    }
    __syncthreads();
    float z = -INFINITY;
    bool act = (node < n) && (lane < NCLS);
    if (act) {
      z = bout[lane];
#pragma unroll 8
      for (int k = 0; k < DHID; ++k) z = fmaf(hl[w][k], Wl[k * NCLS + lane], z);
    }
    float m = z;
#pragma unroll
    for (int off = 32; off; off >>= 1) m = fmaxf(m, __shfl_xor(m, off));
    float p = act ? expf(z - m) : 0.f;
#pragma unroll
    for (int off = 32; off; off >>= 1) p += __shfl_xor(p, off);
    float ls = logf(p);
    if (act) out[(size_t)node * NCLS + lane] = z - m - ls;
    __syncthreads();
  }
}

// ===========================================================================
extern "C" void kernel_launch(void* const* d_in, const int* in_sizes, int n_in,
                              void* d_out, int out_size, void* d_ws, size_t ws_size,
                              hipStream_t stream) {
  const float* x     = (const float*)d_in[0];
  const int*   ei    = (const int*)d_in[1];
  const float* norm  = (const float*)d_in[2];
  const float* W1    = (const float*)d_in[3];
  const float* aW1   = (const float*)d_in[4];
  const float* ab1   = (const float*)d_in[5];
  const float* alpha1= (const float*)d_in[6];
  const float* b1    = (const float*)d_in[7];
  const float* W2    = (const float*)d_in[8];
  const float* aW2   = (const float*)d_in[9];
  const float* ab2   = (const float*)d_in[10];
  const float* alpha2= (const float*)d_in[11];
  const float* b2    = (const float*)d_in[12];
  const float* Wout  = (const float*)d_in[13];
  const float* bout  = (const float*)d_in[14];
  float* out = (float*)d_out;

  const int N  = in_sizes[0] / DHID;
  const int E  = in_sizes[1] / 2;
  const int EP = E + N;

  char* ws = (char*)d_ws;
  size_t off = 0;
  auto alloc = [&](size_t bytes) -> void* {
    void* p = ws + off;
    off += (bytes + 255) & ~(size_t)255;
    return p;
  };
  int*   counts = (int*)  alloc((size_t)N * 4);
  float* ssum   = (float*)alloc((size_t)N * 4);
  float* A      = (float*)alloc((size_t)N * DHID * 4);  // pre-attn H
  float* B      = (float*)alloc((size_t)N * DHID * 4);  // aggregated output
  float* el     = (float*)alloc((size_t)N * 4);
  float* er     = (float*)alloc((size_t)N * 4);
  int*   rowptr = (int*)  alloc((size_t)(N + 1) * 4);
  int*   nxt    = (int*)  alloc((size_t)N * 4);
  int*   srcs   = (int*)  alloc((size_t)EP * 4);
  float* sexp   = (float*)alloc((size_t)EP * 4);

  const int gZero = (N + 255) / 256;
  const int gEdge = (EP + 255) / 256;
  const int gT    = (N + 31) / 32;
  const int gAgg  = (N + 3) / 4;
  const int gHead = (N + 15) / 16;

  // graph-static build
  zero_kernel<<<gZero, 256, 0, stream>>>(counts, ssum, N);
  build_count_kernel<<<gEdge, 256, 0, stream>>>(ei, norm, counts, ssum, E, EP);
  scan_kernel<<<1, 1024, 0, stream>>>(counts, rowptr, nxt, N);
  build_scatter_kernel<<<gEdge, 256, 0, stream>>>(ei, norm, nxt, srcs, sexp,
                                                  E, EP);
  // layer 1
  gemm_elr_kernel<<<gT, 256, 0, stream>>>(x, W1, aW1, A, el, er, N);
  agg_kernel<<<gAgg, 256, 0, stream>>>(A, rowptr, srcs, sexp, el, er, ssum,
                                       ab1, alpha1, b1, B, N);
  // layer 2
  gemm_elr_kernel<<<gT, 256, 0, stream>>>(B, W2, aW2, A, el, er, N);
  agg_kernel<<<gAgg, 256, 0, stream>>>(A, rowptr, srcs, sexp, el, er, ssum,
                                       ab2, alpha2, b2, B, N);
  // head
  head_kernel<<<gHead, 256, 0, stream>>>(B, Wout, bout, out, N);
}

// Round 7
// 185.451 us; speedup vs baseline: 1.1309x; 1.0802x over previous
//
#include <hip/hip_runtime.h>
#include <math.h>

#define DHID 128
#define NCLS 40

typedef unsigned int   u32;
typedef unsigned short u16;

// round-to-nearest-even f32 -> bf16
__device__ __forceinline__ u16 f2bf(float f) {
  u32 u = __float_as_uint(f);
  return (u16)((u + 0x7FFFu + ((u >> 16) & 1u)) >> 16);
}

// ============ zero counts+ssum ==============================================
__global__ __launch_bounds__(256) void zero_kernel(
    int* __restrict__ counts, float* __restrict__ ssum, int n) {
  int i = blockIdx.x * 256 + threadIdx.x;
  if (i < n) { counts[i] = 0; ssum[i] = 0.f; }
}

// ============ CSR build (graph-static, once) ================================
__global__ __launch_bounds__(256) void build_count_kernel(
    const int* __restrict__ ei, const float* __restrict__ norm,
    int* __restrict__ counts, float* __restrict__ ssum, int E, int EP) {
  int k = blockIdx.x * blockDim.x + threadIdx.x;
  if (k >= EP) return;
  int src, dst;
  if (k < E) { src = ei[k]; dst = ei[E + k]; }
  else       { src = dst = k - E; }
  atomicAdd(&counts[dst], 1);
  atomicAdd(&ssum[src], __expf(norm[k]));
}

__global__ __launch_bounds__(1024) void scan_kernel(
    const int* __restrict__ counts, int* __restrict__ rowptr,
    int* __restrict__ nxt, int n) {
  __shared__ int sums[1024];
  int t = threadIdx.x;
  int per = (n + 1023) >> 10;
  int beg = t * per;
  int end = beg + per; if (end > n) end = n; if (beg > n) beg = n;
  int s = 0;
  for (int i = beg; i < end; ++i) s += counts[i];
  sums[t] = s;
  __syncthreads();
  for (int off = 1; off < 1024; off <<= 1) {
    int v = (t >= off) ? sums[t - off] : 0;
    __syncthreads();
    sums[t] += v;
    __syncthreads();
  }
  int run = (t == 0) ? 0 : sums[t - 1];
  for (int i = beg; i < end; ++i) {
    rowptr[i] = run; nxt[i] = run; run += counts[i];
  }
  if (t == 1023) rowptr[n] = sums[1023];
}

// scatter stores raw exp(norm); the 1/ssum[dst] factor is applied in agg
__global__ __launch_bounds__(256) void build_scatter_kernel(
    const int* __restrict__ ei, const float* __restrict__ norm,
    int* __restrict__ nxt, int* __restrict__ srcs, float* __restrict__ sexp,
    int E, int EP) {
  int k = blockIdx.x * blockDim.x + threadIdx.x;
  if (k >= EP) return;
  int src, dst;
  if (k < E) { src = ei[k]; dst = ei[E + k]; }
  else       { src = dst = k - E; }
  int pos = atomicAdd(&nxt[dst], 1);
  srcs[pos] = src;
  sexp[pos] = __expf(norm[k]);
}

// ============ per-node max-aggregation over bf16 H (one wave) ===============
// Lane j owns edge j (first 64): computes e once; denom via shuffle reduce;
// per-edge (w, src) __shfl-broadcast; half-wave gathers 256B bf16 rows
// (uint2 = 4 features per lane), 2 edges in flight per half.
__device__ __forceinline__ float4 agg_node(
    const u16* __restrict__ H, const int* __restrict__ rowptr,
    const int* __restrict__ srcs, const float* __restrict__ sexp,
    const float* __restrict__ el, const float* __restrict__ ssum,
    float base, float al, int node, int lane) {
  int beg = rowptr[node], end = rowptr[node + 1];
  int deg = end - beg;
  int src0 = 0; float e0 = 0.f, sx0 = 0.f;
  if (lane < deg) {
    src0 = srcs[beg + lane];
    sx0  = sexp[beg + lane];
    float g = el[src0] + base;
    e0 = __expf(g > 0.f ? g : 0.2f * g);
  }
  float es = e0;
  for (int cb = beg + 64; cb < end; cb += 64) {   // rare: deg > 64
    int s2 = cb + lane;
    if (s2 < end) {
      float g = el[srcs[s2]] + base;
      es += __expf(g > 0.f ? g : 0.2f * g);
    }
  }
#pragma unroll
  for (int off = 32; off; off >>= 1) es += __shfl_xor(es, off);
  float invEs = al / es;
  float omaS  = (1.f - al) / ssum[node];
  float w0 = e0 * invEs + sx0 * omaS;

  int half = lane >> 5;
  int fl = (lane & 31) << 2;                       // feature idx (x4)
  float4 acc = make_float4(-INFINITY, -INFINITY, -INFINITY, -INFINITY);
  int cnt = deg < 64 ? deg : 64;
  int jj = half;
  for (; jj + 2 < cnt; jj += 4) {
    int   sa = __shfl(src0, jj);
    int   sb = __shfl(src0, jj + 2);
    float wa = __shfl(w0, jj);
    float wb = __shfl(w0, jj + 2);
    uint2 ha = *reinterpret_cast<const uint2*>(H + (size_t)sa * DHID + fl);
    uint2 hb = *reinterpret_cast<const uint2*>(H + (size_t)sb * DHID + fl);
    acc.x = fmaxf(acc.x, fmaxf(wa * __uint_as_float(ha.x << 16),
                               wb * __uint_as_float(hb.x << 16)));
    acc.y = fmaxf(acc.y, fmaxf(wa * __uint_as_float(ha.x & 0xFFFF0000u),
                               wb * __uint_as_float(hb.x & 0xFFFF0000u)));
    acc.z = fmaxf(acc.z, fmaxf(wa * __uint_as_float(ha.y << 16),
                               wb * __uint_as_float(hb.y << 16)));
    acc.w = fmaxf(acc.w, fmaxf(wa * __uint_as_float(ha.y & 0xFFFF0000u),
                               wb * __uint_as_float(hb.y & 0xFFFF0000u)));
  }
  if (jj < cnt) {
    int   sa = __shfl(src0, jj);
    float wa = __shfl(w0, jj);
    uint2 ha = *reinterpret_cast<const uint2*>(H + (size_t)sa * DHID + fl);
    acc.x = fmaxf(acc.x, wa * __uint_as_float(ha.x << 16));
    acc.y = fmaxf(acc.y, wa * __uint_as_float(ha.x & 0xFFFF0000u));
    acc.z = fmaxf(acc.z, wa * __uint_as_float(ha.y << 16));
    acc.w = fmaxf(acc.w, wa * __uint_as_float(ha.y & 0xFFFF0000u));
  }
  for (int cb = beg + 64; cb < end; cb += 64) {   // rare: deg > 64
    int s2 = cb + lane;
    int srcc = 0; float wc = 0.f;
    if (s2 < end) {
      srcc = srcs[s2];
      float g = el[srcc] + base;
      wc = __expf(g > 0.f ? g : 0.2f * g) * invEs + sexp[s2] * omaS;
    }
    int cnt2 = end - cb; if (cnt2 > 64) cnt2 = 64;
    int q = half;
    for (; q < cnt2; q += 2) {
      int   sa = __shfl(srcc, q);
      float wa = __shfl(wc, q);
      uint2 ha = *reinterpret_cast<const uint2*>(H + (size_t)sa * DHID + fl);
      acc.x = fmaxf(acc.x, wa * __uint_as_float(ha.x << 16));
      acc.y = fmaxf(acc.y, wa * __uint_as_float(ha.x & 0xFFFF0000u));
      acc.z = fmaxf(acc.z, wa * __uint_as_float(ha.y << 16));
      acc.w = fmaxf(acc.w, wa * __uint_as_float(ha.y & 0xFFFF0000u));
    }
  }
  acc.x = fmaxf(acc.x, __shfl_xor(acc.x, 32));
  acc.y = fmaxf(acc.y, __shfl_xor(acc.y, 32));
  acc.z = fmaxf(acc.z, __shfl_xor(acc.z, 32));
  acc.w = fmaxf(acc.w, __shfl_xor(acc.w, 32));
  return acc;
}

// ============ standalone agg: Y[node] = relu(max_e w*H[src] + bias) =========
__global__ __launch_bounds__(256) void agg_kernel(
    const u16* __restrict__ H, const int* __restrict__ rowptr,
    const int* __restrict__ srcs, const float* __restrict__ sexp,
    const float* __restrict__ el, const float* __restrict__ er,
    const float* __restrict__ ssum, const float* __restrict__ ab,
    const float* __restrict__ alpha, const float* __restrict__ bias,
    float* __restrict__ Y, int n) {
  int node = blockIdx.x * 4 + (threadIdx.x >> 6);
  int lane = threadIdx.x & 63;
  if (node >= n) return;
  float al = fminf(fmaxf(alpha[0], 1e-4f), 0.9999f);
  float base = er[node] + ab[0];
  float4 acc = agg_node(H, rowptr, srcs, sexp, el, ssum, base, al, node, lane);
  if (lane < 32) {
    int fl = lane << 2;
    float4 b = *reinterpret_cast<const float4*>(bias + fl);
    float4 o;
    o.x = fmaxf(acc.x + b.x, 0.f);
    o.y = fmaxf(acc.y + b.y, 0.f);
    o.z = fmaxf(acc.z + b.z, 0.f);
    o.w = fmaxf(acc.w + b.w, 0.f);
    *reinterpret_cast<float4*>(Y + (size_t)node * DHID + fl) = o;
  }
}

// ============ GEMM+elr: Xs(32x128 LDS) @ W -> Hbf16, el, er =================
__device__ __forceinline__ void gemm_from_lds(
    float* Ws, float* Xs, const float* __restrict__ W,
    const float* __restrict__ aW, u16* __restrict__ Hout,
    float* __restrict__ elo, float* __restrict__ ero, int n, int rowBase) {
  int t = threadIdx.x;
  int rg = t >> 5;
  int c0 = (t & 31) << 2;
  float acc[4][4];
#pragma unroll
  for (int j = 0; j < 4; ++j)
#pragma unroll
    for (int c = 0; c < 4; ++c) acc[j][c] = 0.f;

  for (int kt = 0; kt < 2; ++kt) {
    __syncthreads();
    const float* Wsrc = W + kt * 64 * DHID;
#pragma unroll
    for (int q = 0; q < 8; ++q) {
      int i4 = t + q * 256;
      *reinterpret_cast<float4*>(Ws + i4 * 4) =
          *reinterpret_cast<const float4*>(Wsrc + i4 * 4);
    }
    __syncthreads();
#pragma unroll 2
    for (int k = 0; k < 64; k += 4) {
      float4 xv[4];
#pragma unroll
      for (int j = 0; j < 4; ++j)
        xv[j] = *reinterpret_cast<const float4*>(
            Xs + (rg * 4 + j) * DHID + kt * 64 + k);
#pragma unroll
      for (int kk = 0; kk < 4; ++kk) {
        float4 wv = *reinterpret_cast<const float4*>(Ws + (k + kk) * DHID + c0);
#pragma unroll
        for (int j = 0; j < 4; ++j) {
          float xj = (&xv[j].x)[kk];
          acc[j][0] = fmaf(xj, wv.x, acc[j][0]);
          acc[j][1] = fmaf(xj, wv.y, acc[j][1]);
          acc[j][2] = fmaf(xj, wv.z, acc[j][2]);
          acc[j][3] = fmaf(xj, wv.w, acc[j][3]);
        }
      }
    }
  }

  // write H as bf16 (ushort4 = 8B per thread, 256B per row)
#pragma unroll
  for (int j = 0; j < 4; ++j) {
    int gr = rowBase + rg * 4 + j;
    if (gr < n) {
      ushort4 hv;
      hv.x = f2bf(acc[j][0]); hv.y = f2bf(acc[j][1]);
      hv.z = f2bf(acc[j][2]); hv.w = f2bf(acc[j][3]);
      *reinterpret_cast<ushort4*>(Hout + (size_t)gr * DHID + c0) = hv;
    }
  }

  float4 al4 = *reinterpret_cast<const float4*>(aW + c0);
  float4 ar4 = *reinterpret_cast<const float4*>(aW + DHID + c0);
  __syncthreads();
  float* P = Xs;                    // reuse as P[2][32][33]
#pragma unroll
  for (int j = 0; j < 4; ++j) {
    int r = rg * 4 + j;
    float pl = acc[j][0] * al4.x + acc[j][1] * al4.y +
               acc[j][2] * al4.z + acc[j][3] * al4.w;
    float pr = acc[j][0] * ar4.x + acc[j][1] * ar4.y +
               acc[j][2] * ar4.z + acc[j][3] * ar4.w;
    P[r * 33 + (t & 31)] = pl;
    P[1056 + r * 33 + (t & 31)] = pr;
  }
  __syncthreads();
  if (t < 64) {
    int half = t >> 5, r = t & 31;
    const float* Pr = P + half * 1056 + r * 33;
    float s = 0.f;
#pragma unroll
    for (int c = 0; c < 32; ++c) s += Pr[c];
    int gr = rowBase + r;
    if (gr < n) { if (half) ero[gr] = s; else elo[gr] = s; }
  }
}

__global__ __launch_bounds__(256) void gemm_elr_kernel(
    const float* __restrict__ X, const float* __restrict__ W,
    const float* __restrict__ aW, u16* __restrict__ H,
    float* __restrict__ el, float* __restrict__ er, int n) {
  __shared__ float Ws[64 * 128];
  __shared__ float Xs[32 * 128];
  int t = threadIdx.x;
  int rowBase = blockIdx.x * 32;
#pragma unroll
  for (int q = 0; q < 4; ++q) {
    int i4 = t + q * 256;
    int r = i4 >> 5, c = (i4 & 31) << 2;
    int gr = rowBase + r;
    float4 v = (gr < n)
        ? *reinterpret_cast<const float4*>(X + (size_t)gr * DHID + c)
        : make_float4(0.f, 0.f, 0.f, 0.f);
    *reinterpret_cast<float4*>(Xs + r * DHID + c) = v;
  }
  gemm_from_lds(Ws, Xs, W, aW, H, el, er, n, rowBase);
}

// ============ head: out = log_softmax(H @ Wout + bout), 16 nodes/block =======
__global__ __launch_bounds__(256) void head_kernel(
    const float* __restrict__ H, const float* __restrict__ Wout,
    const float* __restrict__ bout, float* __restrict__ out, int n) {
  __shared__ float Wl[DHID * NCLS];  // 20 KB
  __shared__ float hl[4][DHID];
  int t = threadIdx.x;
  for (int i = t; i < DHID * NCLS; i += 256) Wl[i] = Wout[i];
  int w = t >> 6, lane = t & 63;
  __syncthreads();
  for (int nd = 0; nd < 4; ++nd) {
    int node = blockIdx.x * 16 + nd * 4 + w;
    if (node < n) {
      const float* hrow = H + (size_t)node * DHID;
      hl[w][lane] = hrow[lane];
      hl[w][lane + 64] = hrow[lane + 64];
    }
    __syncthreads();
    float z = -INFINITY;
    bool act = (node < n) && (lane < NCLS);
    if (act) {
      z = bout[lane];
#pragma unroll 8
      for (int k = 0; k < DHID; ++k) z = fmaf(hl[w][k], Wl[k * NCLS + lane], z);
    }
    float m = z;
#pragma unroll
    for (int off = 32; off; off >>= 1) m = fmaxf(m, __shfl_xor(m, off));
    float p = act ? expf(z - m) : 0.f;
#pragma unroll
    for (int off = 32; off; off >>= 1) p += __shfl_xor(p, off);
    float ls = logf(p);
    if (act) out[(size_t)node * NCLS + lane] = z - m - ls;
    __syncthreads();
  }
}

// ===========================================================================
extern "C" void kernel_launch(void* const* d_in, const int* in_sizes, int n_in,
                              void* d_out, int out_size, void* d_ws, size_t ws_size,
                              hipStream_t stream) {
  const float* x     = (const float*)d_in[0];
  const int*   ei    = (const int*)d_in[1];
  const float* norm  = (const float*)d_in[2];
  const float* W1    = (const float*)d_in[3];
  const float* aW1   = (const float*)d_in[4];
  const float* ab1   = (const float*)d_in[5];
  const float* alpha1= (const float*)d_in[6];
  const float* b1    = (const float*)d_in[7];
  const float* W2    = (const float*)d_in[8];
  const float* aW2   = (const float*)d_in[9];
  const float* ab2   = (const float*)d_in[10];
  const float* alpha2= (const float*)d_in[11];
  const float* b2    = (const float*)d_in[12];
  const float* Wout  = (const float*)d_in[13];
  const float* bout  = (const float*)d_in[14];
  float* out = (float*)d_out;

  const int N  = in_sizes[0] / DHID;
  const int E  = in_sizes[1] / 2;
  const int EP = E + N;

  char* ws = (char*)d_ws;
  size_t off = 0;
  auto alloc = [&](size_t bytes) -> void* {
    void* p = ws + off;
    off += (bytes + 255) & ~(size_t)255;
    return p;
  };
  int*   counts = (int*)  alloc((size_t)N * 4);
  float* ssum   = (float*)alloc((size_t)N * 4);
  u16*   Hbf    = (u16*)  alloc((size_t)N * DHID * 2);  // bf16 pre-attn H
  float* B      = (float*)alloc((size_t)N * DHID * 4);  // aggregated output
  float* el     = (float*)alloc((size_t)N * 4);
  float* er     = (float*)alloc((size_t)N * 4);
  int*   rowptr = (int*)  alloc((size_t)(N + 1) * 4);
  int*   nxt    = (int*)  alloc((size_t)N * 4);
  int*   srcs   = (int*)  alloc((size_t)EP * 4);
  float* sexp   = (float*)alloc((size_t)EP * 4);

  const int gZero = (N + 255) / 256;
  const int gEdge = (EP + 255) / 256;
  const int gT    = (N + 31) / 32;
  const int gAgg  = (N + 3) / 4;
  const int gHead = (N + 15) / 16;

  // graph-static build
  zero_kernel<<<gZero, 256, 0, stream>>>(counts, ssum, N);
  build_count_kernel<<<gEdge, 256, 0, stream>>>(ei, norm, counts, ssum, E, EP);
  scan_kernel<<<1, 1024, 0, stream>>>(counts, rowptr, nxt, N);
  build_scatter_kernel<<<gEdge, 256, 0, stream>>>(ei, norm, nxt, srcs, sexp,
                                                  E, EP);
  // layer 1
  gemm_elr_kernel<<<gT, 256, 0, stream>>>(x, W1, aW1, Hbf, el, er, N);
  agg_kernel<<<gAgg, 256, 0, stream>>>(Hbf, rowptr, srcs, sexp, el, er, ssum,
                                       ab1, alpha1, b1, B, N);
  // layer 2
  gemm_elr_kernel<<<gT, 256, 0, stream>>>(B, W2, aW2, Hbf, el, er, N);
  agg_kernel<<<gAgg, 256, 0, stream>>>(Hbf, rowptr, srcs, sexp, el, er, ssum,
                                       ab2, alpha2, b2, B, N);
  // head
  head_kernel<<<gHead, 256, 0, stream>>>(B, Wout, bout, out, N);
}

// Round 8
// 163.867 us; speedup vs baseline: 1.2798x; 1.1317x over previous
//
#include <hip/hip_runtime.h>
#include <math.h>

#define DHID 128
#define NCLS 40

typedef unsigned int   u32;
typedef unsigned short u16;

// round-to-nearest-even f32 -> bf16
__device__ __forceinline__ u16 f2bf(float f) {
  u32 u = __float_as_uint(f);
  return (u16)((u + 0x7FFFu + ((u >> 16) & 1u)) >> 16);
}
__device__ __forceinline__ float bf_lo(u32 p) { return __uint_as_float(p << 16); }
__device__ __forceinline__ float bf_hi(u32 p) { return __uint_as_float(p & 0xFFFF0000u); }

// ============ zero counts+ssum ==============================================
__global__ __launch_bounds__(256) void zero_kernel(
    int* __restrict__ counts, float* __restrict__ ssum, int n) {
  int i = blockIdx.x * 256 + threadIdx.x;
  if (i < n) { counts[i] = 0; ssum[i] = 0.f; }
}

// ============ scan ==========================================================
__global__ __launch_bounds__(1024) void scan_kernel(
    const int* __restrict__ counts, int* __restrict__ rowptr,
    int* __restrict__ nxt, int n) {
  __shared__ int sums[1024];
  int t = threadIdx.x;
  int per = (n + 1023) >> 10;
  int beg = t * per;
  int end = beg + per; if (end > n) end = n; if (beg > n) beg = n;
  int s = 0;
  for (int i = beg; i < end; ++i) s += counts[i];
  sums[t] = s;
  __syncthreads();
  for (int off = 1; off < 1024; off <<= 1) {
    int v = (t >= off) ? sums[t - off] : 0;
    __syncthreads();
    sums[t] += v;
    __syncthreads();
  }
  int run = (t == 0) ? 0 : sums[t - 1];
  for (int i = beg; i < end; ++i) {
    rowptr[i] = run; nxt[i] = run; run += counts[i];
  }
  if (t == 1023) rowptr[n] = sums[1023];
}

// ============ scatter (raw exp(norm); /ssum[dst] applied in agg) ============
__global__ __launch_bounds__(256) void build_scatter_kernel(
    const int* __restrict__ ei, const float* __restrict__ norm,
    int* __restrict__ nxt, int* __restrict__ srcs, float* __restrict__ sexp,
    int E, int EP) {
  int k = blockIdx.x * blockDim.x + threadIdx.x;
  if (k >= EP) return;
  int src, dst;
  if (k < E) { src = ei[k]; dst = ei[E + k]; }
  else       { src = dst = k - E; }
  int pos = atomicAdd(&nxt[dst], 1);
  srcs[pos] = src;
  sexp[pos] = __expf(norm[k]);
}

// ============ GEMM+elr body: Xs(32x128 LDS) @ W -> Hbf16, el, er ============
__device__ __forceinline__ void gemm_from_lds(
    float* Ws, float* Xs, const float* __restrict__ W,
    const float* __restrict__ aW, u16* __restrict__ Hout,
    float* __restrict__ elo, float* __restrict__ ero, int n, int rowBase) {
  int t = threadIdx.x;
  int rg = t >> 5;
  int c0 = (t & 31) << 2;
  float acc[4][4];
#pragma unroll
  for (int j = 0; j < 4; ++j)
#pragma unroll
    for (int c = 0; c < 4; ++c) acc[j][c] = 0.f;

  for (int kt = 0; kt < 2; ++kt) {
    __syncthreads();
    const float* Wsrc = W + kt * 64 * DHID;
#pragma unroll
    for (int q = 0; q < 8; ++q) {
      int i4 = t + q * 256;
      *reinterpret_cast<float4*>(Ws + i4 * 4) =
          *reinterpret_cast<const float4*>(Wsrc + i4 * 4);
    }
    __syncthreads();
#pragma unroll 2
    for (int k = 0; k < 64; k += 4) {
      float4 xv[4];
#pragma unroll
      for (int j = 0; j < 4; ++j)
        xv[j] = *reinterpret_cast<const float4*>(
            Xs + (rg * 4 + j) * DHID + kt * 64 + k);
#pragma unroll
      for (int kk = 0; kk < 4; ++kk) {
        float4 wv = *reinterpret_cast<const float4*>(Ws + (k + kk) * DHID + c0);
#pragma unroll
        for (int j = 0; j < 4; ++j) {
          float xj = (&xv[j].x)[kk];
          acc[j][0] = fmaf(xj, wv.x, acc[j][0]);
          acc[j][1] = fmaf(xj, wv.y, acc[j][1]);
          acc[j][2] = fmaf(xj, wv.z, acc[j][2]);
          acc[j][3] = fmaf(xj, wv.w, acc[j][3]);
        }
      }
    }
  }

#pragma unroll
  for (int j = 0; j < 4; ++j) {
    int gr = rowBase + rg * 4 + j;
    if (gr < n) {
      ushort4 hv;
      hv.x = f2bf(acc[j][0]); hv.y = f2bf(acc[j][1]);
      hv.z = f2bf(acc[j][2]); hv.w = f2bf(acc[j][3]);
      *reinterpret_cast<ushort4*>(Hout + (size_t)gr * DHID + c0) = hv;
    }
  }

  float4 al4 = *reinterpret_cast<const float4*>(aW + c0);
  float4 ar4 = *reinterpret_cast<const float4*>(aW + DHID + c0);
  __syncthreads();
  float* P = Xs;                    // reuse as P[2][32][33]
#pragma unroll
  for (int j = 0; j < 4; ++j) {
    int r = rg * 4 + j;
    float pl = acc[j][0] * al4.x + acc[j][1] * al4.y +
               acc[j][2] * al4.z + acc[j][3] * al4.w;
    float pr = acc[j][0] * ar4.x + acc[j][1] * ar4.y +
               acc[j][2] * ar4.z + acc[j][3] * ar4.w;
    P[r * 33 + (t & 31)] = pl;
    P[1056 + r * 33 + (t & 31)] = pr;
  }
  __syncthreads();
  if (t < 64) {
    int half = t >> 5, r = t & 31;
    const float* Pr = P + half * 1056 + r * 33;
    float s = 0.f;
#pragma unroll
    for (int c = 0; c < 32; ++c) s += Pr[c];
    int gr = rowBase + r;
    if (gr < n) { if (half) ero[gr] = s; else elo[gr] = s; }
  }
}

__device__ __forceinline__ void gemm_stage_x(
    float* Xs, const float* __restrict__ X, int n, int rowBase) {
  int t = threadIdx.x;
#pragma unroll
  for (int q = 0; q < 4; ++q) {
    int i4 = t + q * 256;
    int r = i4 >> 5, c = (i4 & 31) << 2;
    int gr = rowBase + r;
    float4 v = (gr < n)
        ? *reinterpret_cast<const float4*>(X + (size_t)gr * DHID + c)
        : make_float4(0.f, 0.f, 0.f, 0.f);
    *reinterpret_cast<float4*>(Xs + r * DHID + c) = v;
  }
}

// ============ K2: gemm1 (blocks < gT)  ||  build_count (blocks >= gT) =======
__global__ __launch_bounds__(256) void gemm1_count_kernel(
    const float* __restrict__ X, const float* __restrict__ W,
    const float* __restrict__ aW, u16* __restrict__ H,
    float* __restrict__ el, float* __restrict__ er, int n, int gT,
    const int* __restrict__ ei, const float* __restrict__ norm,
    int* __restrict__ counts, float* __restrict__ ssum, int E, int EP) {
  __shared__ float Ws[64 * 128];
  __shared__ float Xs[32 * 128];
  if (blockIdx.x < gT) {
    int rowBase = blockIdx.x * 32;
    gemm_stage_x(Xs, X, n, rowBase);
    gemm_from_lds(Ws, Xs, W, aW, H, el, er, n, rowBase);
  } else {
    int k = (blockIdx.x - gT) * 256 + threadIdx.x;
    if (k < EP) {
      int src, dst;
      if (k < E) { src = ei[k]; dst = ei[E + k]; }
      else       { src = dst = k - E; }
      atomicAdd(&counts[dst], 1);
      atomicAdd(&ssum[src], __expf(norm[k]));
    }
  }
}

// ============ K6: standalone gemm2 ==========================================
__global__ __launch_bounds__(256) void gemm_elr_kernel(
    const float* __restrict__ X, const float* __restrict__ W,
    const float* __restrict__ aW, u16* __restrict__ H,
    float* __restrict__ el, float* __restrict__ er, int n) {
  __shared__ float Ws[64 * 128];
  __shared__ float Xs[32 * 128];
  int rowBase = blockIdx.x * 32;
  gemm_stage_x(Xs, X, n, rowBase);
  gemm_from_lds(Ws, Xs, W, aW, H, el, er, n, rowBase);
}

// ============ per-node max-aggregation over bf16 H (one wave) ===============
// Lane j owns edge j: computes e once; denom via shuffle; per-edge (w,src)
// __shfl-broadcast; half-wave gathers 256B bf16 rows, 3 edges in flight/half.
__device__ __forceinline__ float4 agg_node(
    const u16* __restrict__ H, const int* __restrict__ rowptr,
    const int* __restrict__ srcs, const float* __restrict__ sexp,
    const float* __restrict__ el, const float* __restrict__ ssum,
    float base, float al, int node, int lane) {
  int beg = rowptr[node], end = rowptr[node + 1];
  int deg = end - beg;
  int src0 = 0; float e0 = 0.f, sx0 = 0.f;
  if (lane < deg) {
    src0 = srcs[beg + lane];
    sx0  = sexp[beg + lane];
    float g = el[src0] + base;
    e0 = __expf(g > 0.f ? g : 0.2f * g);
  }
  float es = e0;
  for (int cb = beg + 64; cb < end; cb += 64) {   // rare: deg > 64
    int s2 = cb + lane;
    if (s2 < end) {
      float g = el[srcs[s2]] + base;
      es += __expf(g > 0.f ? g : 0.2f * g);
    }
  }
#pragma unroll
  for (int off = 32; off; off >>= 1) es += __shfl_xor(es, off);
  float invEs = al / es;
  float omaS  = (1.f - al) / ssum[node];
  float w0 = e0 * invEs + sx0 * omaS;

  int half = lane >> 5;
  int fl = (lane & 31) << 2;                       // feature idx (x4)
  float4 acc = make_float4(-INFINITY, -INFINITY, -INFINITY, -INFINITY);
  int cnt = deg < 64 ? deg : 64;
  int jj = half;
  // 3 edges in flight per half: jj, jj+2, jj+4; step 6
  for (; jj + 4 < cnt; jj += 6) {
    int   sa = __shfl(src0, jj);
    int   sb = __shfl(src0, jj + 2);
    int   sc = __shfl(src0, jj + 4);
    float wa = __shfl(w0, jj);
    float wb = __shfl(w0, jj + 2);
    float wc = __shfl(w0, jj + 4);
    uint2 ha = *reinterpret_cast<const uint2*>(H + (size_t)sa * DHID + fl);
    uint2 hb = *reinterpret_cast<const uint2*>(H + (size_t)sb * DHID + fl);
    uint2 hc = *reinterpret_cast<const uint2*>(H + (size_t)sc * DHID + fl);
    acc.x = fmaxf(acc.x, fmaxf(fmaxf(wa * bf_lo(ha.x), wb * bf_lo(hb.x)),
                               wc * bf_lo(hc.x)));
    acc.y = fmaxf(acc.y, fmaxf(fmaxf(wa * bf_hi(ha.x), wb * bf_hi(hb.x)),
                               wc * bf_hi(hc.x)));
    acc.z = fmaxf(acc.z, fmaxf(fmaxf(wa * bf_lo(ha.y), wb * bf_lo(hb.y)),
                               wc * bf_lo(hc.y)));
    acc.w = fmaxf(acc.w, fmaxf(fmaxf(wa * bf_hi(ha.y), wb * bf_hi(hb.y)),
                               wc * bf_hi(hc.y)));
  }
  // tail: at most 2 edges remain for this half (jj, jj+2)
#pragma unroll 1
  for (; jj < cnt; jj += 2) {
    int   sa = __shfl(src0, jj);
    float wa = __shfl(w0, jj);
    uint2 ha = *reinterpret_cast<const uint2*>(H + (size_t)sa * DHID + fl);
    acc.x = fmaxf(acc.x, wa * bf_lo(ha.x));
    acc.y = fmaxf(acc.y, wa * bf_hi(ha.x));
    acc.z = fmaxf(acc.z, wa * bf_lo(ha.y));
    acc.w = fmaxf(acc.w, wa * bf_hi(ha.y));
  }
  for (int cb = beg + 64; cb < end; cb += 64) {   // rare: deg > 64
    int s2 = cb + lane;
    int srcc = 0; float wcv = 0.f;
    if (s2 < end) {
      srcc = srcs[s2];
      float g = el[srcc] + base;
      wcv = __expf(g > 0.f ? g : 0.2f * g) * invEs + sexp[s2] * omaS;
    }
    int cnt2 = end - cb; if (cnt2 > 64) cnt2 = 64;
    int q = half;
    for (; q < cnt2; q += 2) {
      int   sa = __shfl(srcc, q);
      float wa = __shfl(wcv, q);
      uint2 ha = *reinterpret_cast<const uint2*>(H + (size_t)sa * DHID + fl);
      acc.x = fmaxf(acc.x, wa * bf_lo(ha.x));
      acc.y = fmaxf(acc.y, wa * bf_hi(ha.x));
      acc.z = fmaxf(acc.z, wa * bf_lo(ha.y));
      acc.w = fmaxf(acc.w, wa * bf_hi(ha.y));
    }
  }
  acc.x = fmaxf(acc.x, __shfl_xor(acc.x, 32));
  acc.y = fmaxf(acc.y, __shfl_xor(acc.y, 32));
  acc.z = fmaxf(acc.z, __shfl_xor(acc.z, 32));
  acc.w = fmaxf(acc.w, __shfl_xor(acc.w, 32));
  return acc;
}

// ============ K5: agg1 -> B (fp32) ==========================================
__global__ __launch_bounds__(256) void agg_kernel(
    const u16* __restrict__ H, const int* __restrict__ rowptr,
    const int* __restrict__ srcs, const float* __restrict__ sexp,
    const float* __restrict__ el, const float* __restrict__ er,
    const float* __restrict__ ssum, const float* __restrict__ ab,
    const float* __restrict__ alpha, const float* __restrict__ bias,
    float* __restrict__ Y, int n) {
  int node = blockIdx.x * 4 + (threadIdx.x >> 6);
  int lane = threadIdx.x & 63;
  if (node >= n) return;
  float al = fminf(fmaxf(alpha[0], 1e-4f), 0.9999f);
  float base = er[node] + ab[0];
  float4 acc = agg_node(H, rowptr, srcs, sexp, el, ssum, base, al, node, lane);
  if (lane < 32) {
    int fl = lane << 2;
    float4 b = *reinterpret_cast<const float4*>(bias + fl);
    float4 o;
    o.x = fmaxf(acc.x + b.x, 0.f);
    o.y = fmaxf(acc.y + b.y, 0.f);
    o.z = fmaxf(acc.z + b.z, 0.f);
    o.w = fmaxf(acc.w + b.w, 0.f);
    *reinterpret_cast<float4*>(Y + (size_t)node * DHID + fl) = o;
  }
}

// ============ K7: agg2 + head (same grid shape as agg: 4 nodes/block) =======
__global__ __launch_bounds__(256) void agg_head_kernel(
    const u16* __restrict__ H, const int* __restrict__ rowptr,
    const int* __restrict__ srcs, const float* __restrict__ sexp,
    const float* __restrict__ el, const float* __restrict__ er,
    const float* __restrict__ ssum, const float* __restrict__ ab,
    const float* __restrict__ alpha, const float* __restrict__ bias,
    const float* __restrict__ Wout, const float* __restrict__ bout,
    float* __restrict__ out, int n) {
  __shared__ float Wl[DHID * NCLS];   // 20 KB
  __shared__ float hl[4][DHID];       // 2 KB
  int t = threadIdx.x;
  for (int i = t; i < DHID * NCLS; i += 256) Wl[i] = Wout[i];
  int wv = t >> 6, lane = t & 63;
  int node = blockIdx.x * 4 + wv;
  if (node < n) {                      // wave-uniform branch
    float al = fminf(fmaxf(alpha[0], 1e-4f), 0.9999f);
    float base = er[node] + ab[0];
    float4 acc = agg_node(H, rowptr, srcs, sexp, el, ssum, base, al, node, lane);
    if (lane < 32) {
      int fl = lane << 2;
      float4 b = *reinterpret_cast<const float4*>(bias + fl);
      hl[wv][fl]     = fmaxf(acc.x + b.x, 0.f);
      hl[wv][fl + 1] = fmaxf(acc.y + b.y, 0.f);
      hl[wv][fl + 2] = fmaxf(acc.z + b.z, 0.f);
      hl[wv][fl + 3] = fmaxf(acc.w + b.w, 0.f);
    }
  }
  __syncthreads();
  if (node >= n) return;
  float z = -INFINITY;
  bool act = lane < NCLS;
  if (act) {
    z = bout[lane];
    const float* hr = hl[wv];
#pragma unroll 8
    for (int k = 0; k < DHID; ++k) z = fmaf(hr[k], Wl[k * NCLS + lane], z);
  }
  float m = z;
#pragma unroll
  for (int off = 32; off; off >>= 1) m = fmaxf(m, __shfl_xor(m, off));
  float p = act ? expf(z - m) : 0.f;
#pragma unroll
  for (int off = 32; off; off >>= 1) p += __shfl_xor(p, off);
  float ls = logf(p);
  if (act) out[(size_t)node * NCLS + lane] = z - m - ls;
}

// ===========================================================================
extern "C" void kernel_launch(void* const* d_in, const int* in_sizes, int n_in,
                              void* d_out, int out_size, void* d_ws, size_t ws_size,
                              hipStream_t stream) {
  const float* x     = (const float*)d_in[0];
  const int*   ei    = (const int*)d_in[1];
  const float* norm  = (const float*)d_in[2];
  const float* W1    = (const float*)d_in[3];
  const float* aW1   = (const float*)d_in[4];
  const float* ab1   = (const float*)d_in[5];
  const float* alpha1= (const float*)d_in[6];
  const float* b1    = (const float*)d_in[7];
  const float* W2    = (const float*)d_in[8];
  const float* aW2   = (const float*)d_in[9];
  const float* ab2   = (const float*)d_in[10];
  const float* alpha2= (const float*)d_in[11];
  const float* b2    = (const float*)d_in[12];
  const float* Wout  = (const float*)d_in[13];
  const float* bout  = (const float*)d_in[14];
  float* out = (float*)d_out;

  const int N  = in_sizes[0] / DHID;
  const int E  = in_sizes[1] / 2;
  const int EP = E + N;

  char* ws = (char*)d_ws;
  size_t off = 0;
  auto alloc = [&](size_t bytes) -> void* {
    void* p = ws + off;
    off += (bytes + 255) & ~(size_t)255;
    return p;
  };
  int*   counts = (int*)  alloc((size_t)N * 4);
  float* ssum   = (float*)alloc((size_t)N * 4);
  u16*   Hbf    = (u16*)  alloc((size_t)N * DHID * 2);  // bf16 pre-attn H
  float* B      = (float*)alloc((size_t)N * DHID * 4);  // layer-1 aggregated
  float* el     = (float*)alloc((size_t)N * 4);
  float* er     = (float*)alloc((size_t)N * 4);
  int*   rowptr = (int*)  alloc((size_t)(N + 1) * 4);
  int*   nxt    = (int*)  alloc((size_t)N * 4);
  int*   srcs   = (int*)  alloc((size_t)EP * 4);
  float* sexp   = (float*)alloc((size_t)EP * 4);

  const int gZero = (N + 255) / 256;
  const int gEdge = (EP + 255) / 256;
  const int gT    = (N + 31) / 32;
  const int gAgg  = (N + 3) / 4;

  // K1: zero
  zero_kernel<<<gZero, 256, 0, stream>>>(counts, ssum, N);
  // K2: gemm1 || build_count (independent work packed in one launch)
  gemm1_count_kernel<<<gT + gEdge, 256, 0, stream>>>(
      x, W1, aW1, Hbf, el, er, N, gT, ei, norm, counts, ssum, E, EP);
  // K3: scan
  scan_kernel<<<1, 1024, 0, stream>>>(counts, rowptr, nxt, N);
  // K4: scatter
  build_scatter_kernel<<<gEdge, 256, 0, stream>>>(ei, norm, nxt, srcs, sexp,
                                                  E, EP);
  // K5: agg layer 1 -> B
  agg_kernel<<<gAgg, 256, 0, stream>>>(Hbf, rowptr, srcs, sexp, el, er, ssum,
                                       ab1, alpha1, b1, B, N);
  // K6: gemm2
  gemm_elr_kernel<<<gT, 256, 0, stream>>>(B, W2, aW2, Hbf, el, er, N);
  // K7: agg layer 2 + head
  agg_head_kernel<<<gAgg, 256, 0, stream>>>(Hbf, rowptr, srcs, sexp, el, er,
                                            ssum, ab2, alpha2, b2, Wout, bout,
                                            out, N);
}